// Round 3
// baseline (327.067 us; speedup 1.0000x reference)
//
#include <hip/hip_runtime.h>
#include <hip/hip_bf16.h>
#include <hip/hip_cooperative_groups.h>

namespace cg = cooperative_groups;

#define NDIM   512
#define NPOS   1024   // 32*32
#define NB     8
#define INNER  1536
#define DHEAD  64

typedef __attribute__((ext_vector_type(8))) short bf8v;   // 8 bf16 = 4 VGPRs
typedef __attribute__((ext_vector_type(4))) float f4v;

__device__ __forceinline__ f4v mfma16(bf8v a, bf8v b, f4v c) {
    return __builtin_amdgcn_mfma_f32_16x16x32_bf16(a, b, c, 0, 0, 0);
}

__device__ __forceinline__ unsigned short f2bs(float v) {
    __hip_bfloat16 h = __float2bfloat16(v);   // RNE
    return *reinterpret_cast<unsigned short*>(&h);
}

// async global->LDS, 16B per lane; lds dst = wave-uniform base + lane*16
__device__ __forceinline__ void gl_lds16(const unsigned short* g, unsigned short* l) {
    __builtin_amdgcn_global_load_lds(
        (const __attribute__((address_space(1))) void*)g,
        (__attribute__((address_space(3))) void*)l,
        16, 0, 0);
}

// ===================== MEGA KERNEL (cooperative, 4 phases) =====================
// 512 blocks x 256 threads, 2 blocks/CU co-resident. LDS union 51200 B.
__global__ __launch_bounds__(256, 2) void mega_kernel(
    const float* __restrict__ x, const float* __restrict__ gamma,
    const float* __restrict__ wq32, const float* __restrict__ wo32,
    unsigned short* __restrict__ xnT, unsigned short* __restrict__ wqb,
    unsigned short* __restrict__ wob, unsigned short* __restrict__ qT,
    unsigned short* __restrict__ kT, unsigned short* __restrict__ vv,
    unsigned short* __restrict__ attnT, float* __restrict__ outp)
{
    __shared__ __align__(16) unsigned char SM[51200];
    cg::grid_group grid = cg::this_grid();
    const int t = threadIdx.x;

    // ---------------- P1: LN+transpose (vb 0..255) + weight cast (vb 256..1279)
    {
        float* ssum   = (float*)SM;                    // [8][32]
        float* ssq    = (float*)(SM + 1024);           // [8][32]
        float* mean_s = (float*)(SM + 2048);           // [32]
        float* rstd_s = (float*)(SM + 2176);           // [32]
        unsigned short (*tile)[72] = (unsigned short(*)[72])(SM + 2304);  // [32][72]
        for (int vb = blockIdx.x; vb < 1280; vb += 512) {
            if (vb >= 256) {
                const int n1 = INNER * NDIM / 4;
                int i = (vb - 256) * 256 + t;
                const float* src; unsigned short* dst; int j;
                if (i < n1) { src = wq32; dst = wqb; j = i; }
                else        { src = wo32; dst = wob; j = i - n1; }
                float4 v = ((const float4*)src)[j];
                ushort4 u;
                u.x = f2bs(v.x); u.y = f2bs(v.y); u.z = f2bs(v.z); u.w = f2bs(v.w);
                ((ushort4*)dst)[j] = u;
                continue;
            }
            const int b = vb >> 5;
            const int n0 = (vb & 31) * 32;
            {
                const int ln = t & 31, cgp = t >> 5;   // 8 channel-groups x 64 ch
                const float* xp = x + (size_t)b * NDIM * NPOS + n0 + ln;
                float s = 0.f, ss = 0.f;
#pragma unroll 8
                for (int c = cgp * 64; c < cgp * 64 + 64; ++c) {
                    float v = xp[(size_t)c * NPOS];
                    s += v; ss += v * v;
                }
                ssum[cgp * 32 + ln] = s; ssq[cgp * 32 + ln] = ss;
            }
            __syncthreads();
            if (t < 32) {
                float st = 0.f, sq = 0.f;
#pragma unroll
                for (int g = 0; g < 8; ++g) { st += ssum[g * 32 + t]; sq += ssq[g * 32 + t]; }
                float m = st * (1.0f / NDIM);
                float var = sq * (1.0f / NDIM) - m * m;
                mean_s[t] = m;
                rstd_s[t] = rsqrtf(var + 1e-5f);
            }
            __syncthreads();

            const int cl = t >> 2, nq = (t & 3) * 8;   // load/normalize indexing
            const int nr = t >> 3, ch = (t & 7) * 8;   // store indexing
            for (int c0 = 0; c0 < NDIM; c0 += 64) {
                const float g = gamma[c0 + cl];
                const float* xp = x + ((size_t)b * NDIM + c0 + cl) * NPOS + n0 + nq;
                float4 v0 = *(const float4*)(xp);
                float4 v1 = *(const float4*)(xp + 4);
                float4 m0 = *(const float4*)&mean_s[nq];
                float4 m1 = *(const float4*)&mean_s[nq + 4];
                float4 r0 = *(const float4*)&rstd_s[nq];
                float4 r1 = *(const float4*)&rstd_s[nq + 4];
                tile[nq + 0][cl] = f2bs((v0.x - m0.x) * r0.x * g);
                tile[nq + 1][cl] = f2bs((v0.y - m0.y) * r0.y * g);
                tile[nq + 2][cl] = f2bs((v0.z - m0.z) * r0.z * g);
                tile[nq + 3][cl] = f2bs((v0.w - m0.w) * r0.w * g);
                tile[nq + 4][cl] = f2bs((v1.x - m1.x) * r1.x * g);
                tile[nq + 5][cl] = f2bs((v1.y - m1.y) * r1.y * g);
                tile[nq + 6][cl] = f2bs((v1.z - m1.z) * r1.z * g);
                tile[nq + 7][cl] = f2bs((v1.w - m1.w) * r1.w * g);
                __syncthreads();
                unsigned short* dst = xnT + ((size_t)b * NPOS + n0 + nr) * NDIM + c0 + ch;
                *(uint4*)dst = *(const uint4*)&tile[nr][ch];
                __syncthreads();
            }
        }
    }
    grid.sync();

    // ---------------- P2: QKV GEMM (vb 0..767) ----------------
    {
        unsigned short* smem = (unsigned short*)SM;   // 36864 B used
        const int w = t >> 6, lane = t & 63;
        const int l15 = lane & 15, quad = lane >> 4;
        const int wm = (w >> 1) * 64, wn = (w & 1) * 64;
        const int rl = lane >> 2, sl = lane & 3;
        const int cw = (sl ^ ((rl >> 1) & 3)) * 8;      // write-side global chunk
        const int sA = (quad ^ ((l15 >> 1) & 3)) * 8;   // read-side LDS slot

        for (int vb = blockIdx.x; vb < 768; vb += 512) {
            __syncthreads();   // SM reuse guard across vb iterations
            const int n0 = (vb & 7) * 128;
            const int mi = vb >> 3;                 // 0..95
            const int b  = mi / 12;
            const int m0 = (mi - b * 12) * 128;
            const unsigned short* Abase = wqb + (size_t)m0 * NDIM;
            const unsigned short* Bbase = xnT + ((size_t)b * NPOS + n0) * NDIM;

            f4v acc[4][4];
#pragma unroll
            for (int i = 0; i < 4; ++i)
#pragma unroll
                for (int j = 0; j < 4; ++j) { acc[i][j][0]=0.f; acc[i][j][1]=0.f; acc[i][j][2]=0.f; acc[i][j][3]=0.f; }

            // prologue: stage tile k0=0 into buffer 0
#pragma unroll
            for (int e = 0; e < 2; ++e) {
                const int seg = w * 2 + e;                  // 0..7, 16 rows each
                const int r = seg * 16 + rl;
                gl_lds16(Abase + (size_t)r * NDIM + cw, smem + seg * 512);
                gl_lds16(Bbase + (size_t)r * NDIM + cw, smem + 4096 + seg * 512);
            }

            for (int k0 = 0; k0 < NDIM; k0 += 32) {
                const int cur = (k0 >> 5) & 1;
                unsigned short* At = smem + cur * 8192;
                unsigned short* Bt = At + 4096;
                __syncthreads();   // vmcnt(0): tile-cur DMA done; prev reads done
                if (k0 + 32 < NDIM) {
                    unsigned short* An = smem + (cur ^ 1) * 8192;
#pragma unroll
                    for (int e = 0; e < 2; ++e) {
                        const int seg = w * 2 + e;
                        const int r = seg * 16 + rl;
                        gl_lds16(Abase + (size_t)r * NDIM + k0 + 32 + cw, An + seg * 512);
                        gl_lds16(Bbase + (size_t)r * NDIM + k0 + 32 + cw, An + 4096 + seg * 512);
                    }
                }
                bf8v af[4], bfr[4];
#pragma unroll
                for (int ms = 0; ms < 4; ++ms) af[ms]  = *(const bf8v*)&At[(wm + ms * 16 + l15) * 32 + sA];
#pragma unroll
                for (int ns = 0; ns < 4; ++ns) bfr[ns] = *(const bf8v*)&Bt[(wn + ns * 16 + l15) * 32 + sA];
#pragma unroll
                for (int ms = 0; ms < 4; ++ms)
#pragma unroll
                    for (int ns = 0; ns < 4; ++ns)
                        acc[ms][ns] = mfma16(af[ms], bfr[ns], acc[ms][ns]);
            }
            __syncthreads();   // done with dbuf; smem reusable as bounce

            const int sec = m0 >> 9;         // 0=q, 1=k, 2=v
            const int om  = m0 & 511;
            if (sec == 2) {
                unsigned short (*bw)[72] = (unsigned short(*)[72])(smem + w * 64 * 72);
                unsigned short* vbase = vv + ((size_t)b * NDIM + om) * NPOS + n0;
#pragma unroll
                for (int ms = 0; ms < 4; ++ms)
#pragma unroll
                    for (int ns = 0; ns < 4; ++ns)
#pragma unroll
                        for (int r = 0; r < 4; ++r)
                            bw[ms * 16 + quad * 4 + r][ns * 16 + l15] = f2bs(acc[ms][ns][r]);
#pragma unroll
                for (int r2 = 0; r2 < 4; ++r2) {
                    const int ml = r2 * 16 + (lane >> 2);
                    unsigned short* dstr = vbase + (size_t)(wm + ml) * NPOS + wn + (lane & 3) * 8;
                    *(uint4*)dstr        = *(const uint4*)&bw[ml][(lane & 3) * 8];
                    *(uint4*)(dstr + 32) = *(const uint4*)&bw[ml][32 + (lane & 3) * 8];
                }
            } else {
                // fold dim_head^-0.5 AND log2(e) into Q: attn uses exp2 directly
                const float qsc = (sec == 0) ? 0.18033688f : 1.0f;   // 0.125*1.4426950
                unsigned short* gT = (sec == 0 ? qT : kT) + ((size_t)b * NPOS + n0) * NDIM + om;
                unsigned short (*bw)[72] = (unsigned short(*)[72])(smem + w * 64 * 72);
#pragma unroll
                for (int ms = 0; ms < 4; ++ms)
#pragma unroll
                    for (int ns = 0; ns < 4; ++ns)
#pragma unroll
                        for (int r = 0; r < 4; ++r)
                            bw[ns * 16 + l15][ms * 16 + quad * 4 + r] = f2bs(acc[ms][ns][r] * qsc);
#pragma unroll
                for (int r2 = 0; r2 < 4; ++r2) {
                    const int nl = r2 * 16 + (lane >> 2);
                    unsigned short* dstr = gT + (size_t)(wn + nl) * NDIM + wm + (lane & 3) * 8;
                    *(uint4*)dstr        = *(const uint4*)&bw[nl][(lane & 3) * 8];
                    *(uint4*)(dstr + 32) = *(const uint4*)&bw[nl][32 + (lane & 3) * 8];
                }
            }
        }
    }
    grid.sync();

    // ---------------- P3: flash attention (one tile per block) ----------------
    {
        unsigned short* KbB = (unsigned short*)SM;               // [2][4096]
        unsigned short* VbB = (unsigned short*)(SM + 16384);     // [2][4096]
        unsigned short (*Ps)[32][72] = (unsigned short(*)[32][72])(SM + 32768);

        const int blk = blockIdx.x;                 // 512
        const int xg = blk & 7, rr = blk >> 3;
        const int i0 = (rr & 7) * 128;
        const int bh = ((rr >> 3) << 3) | xg;
        const int b = bh >> 3, h = bh & 7;

        const int w = t >> 6, lane = t & 63;
        const int l15 = lane & 15, quad = lane >> 4;

        const unsigned short* kbase = kT + (size_t)b * NPOS * NDIM + h * DHEAD;
        const unsigned short* vbase = vv + ((size_t)b * NDIM + h * DHEAD) * NPOS;

        bf8v bq[2][2];
#pragma unroll
        for (int g = 0; g < 2; ++g) {
            const unsigned short* qrow =
                qT + ((size_t)b * NPOS + i0 + w * 32 + g * 16 + l15) * NDIM + h * DHEAD;
            bq[g][0] = *(const bf8v*)(qrow + quad * 8);
            bq[g][1] = *(const bf8v*)(qrow + 32 + quad * 8);
        }

        bf8v bones;   // constant ones fragment: l = sum_j P[i][j]
#pragma unroll
        for (int e = 0; e < 8; ++e) bones[e] = (short)0x3F80;

        const int rloc = lane >> 3;
        const int gch = ((lane & 7) ^ (rloc & 7)) * 8;
        const int sw0 = (quad ^ (l15 & 7)) * 8;
        const int sw1 = ((4 + quad) ^ (l15 & 7)) * 8;

        // prologue: stage tile 0 into buffer 0
#pragma unroll
        for (int e = 0; e < 2; ++e) {
            const int seg = w * 2 + e;
            const int row = seg * 8 + rloc;
            gl_lds16(kbase + (size_t)row * NDIM + gch, KbB + seg * 512);
            gl_lds16(vbase + (size_t)row * NPOS + gch, VbB + seg * 512);
        }

        f4v oc[2][5];
#pragma unroll
        for (int mg = 0; mg < 2; ++mg)
#pragma unroll
            for (int cs = 0; cs < 5; ++cs) { oc[mg][cs][0]=0.f; oc[mg][cs][1]=0.f; oc[mg][cs][2]=0.f; oc[mg][cs][3]=0.f; }

#pragma unroll 2
        for (int j0 = 0; j0 < NPOS; j0 += 64) {
            const int cur = (j0 >> 6) & 1, nxt = cur ^ 1;
            unsigned short* Kc = KbB + cur * 4096;
            unsigned short* Vc = VbB + cur * 4096;
            __syncthreads();   // tile-cur DMA done; reads of nxt done
            if (j0 + 64 < NPOS) {
#pragma unroll
                for (int e = 0; e < 2; ++e) {
                    const int seg = w * 2 + e;
                    const int row = seg * 8 + rloc;
                    gl_lds16(kbase + (size_t)(j0 + 64 + row) * NDIM + gch, KbB + nxt * 4096 + seg * 512);
                    gl_lds16(vbase + (size_t)row * NPOS + j0 + 64 + gch, VbB + nxt * 4096 + seg * 512);
                }
            }

            // ---- phase A: all 16 QK^T MFMAs ----
            f4v sacc[4][2];
            __builtin_amdgcn_s_setprio(1);
#pragma unroll
            for (int jt = 0; jt < 4; ++jt) {
                const int krow = (jt * 16 + l15) * 64;
                bf8v ak0 = *(const bf8v*)&Kc[krow + sw0];
                bf8v ak1 = *(const bf8v*)&Kc[krow + sw1];
#pragma unroll
                for (int g = 0; g < 2; ++g) {
                    f4v s; s[0]=0.f; s[1]=0.f; s[2]=0.f; s[3]=0.f;
                    s = mfma16(ak0, bq[g][0], s);
                    sacc[jt][g] = mfma16(ak1, bq[g][1], s);
                }
            }
            __builtin_amdgcn_s_setprio(0);

            // ---- phase B: batch exp2 + pack + Ps write ----
#pragma unroll
            for (int jt = 0; jt < 4; ++jt)
#pragma unroll
                for (int g = 0; g < 2; ++g) {
                    ushort4 pu;
                    pu.x = f2bs(__builtin_amdgcn_exp2f(sacc[jt][g][0]));
                    pu.y = f2bs(__builtin_amdgcn_exp2f(sacc[jt][g][1]));
                    pu.z = f2bs(__builtin_amdgcn_exp2f(sacc[jt][g][2]));
                    pu.w = f2bs(__builtin_amdgcn_exp2f(sacc[jt][g][3]));
                    *(ushort4*)&Ps[w][g * 16 + l15][jt * 16 + quad * 4] = pu;
                }

            // ---- phase C: PV MFMAs ----
            bf8v ap[2][2];
#pragma unroll
            for (int mg = 0; mg < 2; ++mg) {
                ap[mg][0] = *(const bf8v*)&Ps[w][mg * 16 + l15][quad * 8];
                ap[mg][1] = *(const bf8v*)&Ps[w][mg * 16 + l15][32 + quad * 8];
            }
            __builtin_amdgcn_s_setprio(1);
#pragma unroll
            for (int cs = 0; cs < 4; ++cs) {
                const int vrow = (cs * 16 + l15) * 64;
                bf8v bv0 = *(const bf8v*)&Vc[vrow + sw0];
                bf8v bv1 = *(const bf8v*)&Vc[vrow + sw1];
#pragma unroll
                for (int mg = 0; mg < 2; ++mg) {
                    oc[mg][cs] = mfma16(ap[mg][0], bv0, oc[mg][cs]);
                    oc[mg][cs] = mfma16(ap[mg][1], bv1, oc[mg][cs]);
                }
            }
#pragma unroll
            for (int mg = 0; mg < 2; ++mg) {
                oc[mg][4] = mfma16(ap[mg][0], bones, oc[mg][4]);
                oc[mg][4] = mfma16(ap[mg][1], bones, oc[mg][4]);
            }
            __builtin_amdgcn_s_setprio(0);
        }

        // epilogue: normalize, bounce through Ps[w] stripe, vector stores
#pragma unroll
        for (int mg = 0; mg < 2; ++mg) {
            float inv[4];
#pragma unroll
            for (int r = 0; r < 4; ++r) inv[r] = __builtin_amdgcn_rcpf(oc[mg][4][r]);
#pragma unroll
            for (int cs = 0; cs < 4; ++cs)
#pragma unroll
                for (int r = 0; r < 4; ++r)
                    Ps[w][mg * 16 + quad * 4 + r][cs * 16 + l15] = f2bs(oc[mg][cs][r] * inv[r]);
        }
        {
            const int br = lane >> 1;
            const int bc = lane & 1;
            unsigned short* dst =
                attnT + ((size_t)b * NPOS + i0 + w * 32 + br) * NDIM + h * DHEAD;
#pragma unroll
            for (int q2 = 0; q2 < 4; ++q2)
                *(uint4*)(dst + (q2 * 2 + bc) * 8) = *(const uint4*)&Ps[w][br][(q2 * 2 + bc) * 8];
        }
    }
    grid.sync();

    // ---------------- P4: out projection + residual (one tile per block) ------
    {
        unsigned short* smem = (unsigned short*)SM;   // 24576 B used

        const int vb = blockIdx.x;
        const int n0 = (vb & 7) * 128;
        const int m0 = ((vb >> 3) & 7) * 64;
        const int b  = vb >> 6;

        const int w = t >> 6, lane = t & 63;
        const int l15 = lane & 15, quad = lane >> 4;
        const int wm = (w >> 1) * 32, wn = (w & 1) * 64;
        const unsigned short* Abase = wob + (size_t)m0 * NDIM;
        const unsigned short* Bbase = attnT + ((size_t)b * NPOS + n0) * NDIM;

        const int rl = lane >> 2, sl = lane & 3;
        const int cw = (sl ^ ((rl >> 1) & 3)) * 8;
        const int sA = (quad ^ ((l15 >> 1) & 3)) * 8;

        f4v acc[2][4];
#pragma unroll
        for (int i = 0; i < 2; ++i)
#pragma unroll
            for (int j = 0; j < 4; ++j) { acc[i][j][0]=0.f; acc[i][j][1]=0.f; acc[i][j][2]=0.f; acc[i][j][3]=0.f; }

        // prologue: stage tile k0=0 into buffer 0
        {
            const int r = w * 16 + rl;
            gl_lds16(Abase + (size_t)r * NDIM + cw, smem + w * 512);
#pragma unroll
            for (int e = 0; e < 2; ++e) {
                const int seg = w * 2 + e;
                const int rb = seg * 16 + rl;
                gl_lds16(Bbase + (size_t)rb * NDIM + cw, smem + 2048 + seg * 512);
            }
        }

        for (int k0 = 0; k0 < NDIM; k0 += 32) {
            const int cur = (k0 >> 5) & 1;
            unsigned short* At = smem + cur * 6144;
            unsigned short* Bt = At + 2048;
            __syncthreads();
            if (k0 + 32 < NDIM) {
                unsigned short* An = smem + (cur ^ 1) * 6144;
                const int r = w * 16 + rl;
                gl_lds16(Abase + (size_t)r * NDIM + k0 + 32 + cw, An + w * 512);
#pragma unroll
                for (int e = 0; e < 2; ++e) {
                    const int seg = w * 2 + e;
                    const int rb = seg * 16 + rl;
                    gl_lds16(Bbase + (size_t)rb * NDIM + k0 + 32 + cw, An + 2048 + seg * 512);
                }
            }
            bf8v af[2], bfr[4];
#pragma unroll
            for (int ms = 0; ms < 2; ++ms) af[ms]  = *(const bf8v*)&At[(wm + ms * 16 + l15) * 32 + sA];
#pragma unroll
            for (int ns = 0; ns < 4; ++ns) bfr[ns] = *(const bf8v*)&Bt[(wn + ns * 16 + l15) * 32 + sA];
#pragma unroll
            for (int ms = 0; ms < 2; ++ms)
#pragma unroll
                for (int ns = 0; ns < 4; ++ns)
                    acc[ms][ns] = mfma16(af[ms], bfr[ns], acc[ms][ns]);
        }
        const float* xb = x + ((size_t)b * NDIM + m0) * NPOS + n0;
        float* ob = outp + ((size_t)b * NDIM + m0) * NPOS + n0;
#pragma unroll
        for (int ms = 0; ms < 2; ++ms)
#pragma unroll
            for (int r = 0; r < 4; ++r) {
                int m = wm + ms * 16 + quad * 4 + r;
#pragma unroll
                for (int ns = 0; ns < 4; ++ns) {
                    int n = wn + ns * 16 + l15;
                    ob[(size_t)m * NPOS + n] = acc[ms][ns][r] + xb[(size_t)m * NPOS + n];
                }
            }
    }
}

// ===================== Fallback: original 4-kernel chain =====================

__global__ __launch_bounds__(256) void prep_kernel(
    const float* __restrict__ x, const float* __restrict__ gamma,
    const float* __restrict__ wq, const float* __restrict__ wo,
    unsigned short* __restrict__ xnT, unsigned short* __restrict__ wqb,
    unsigned short* __restrict__ wob)
{
    const int blk = blockIdx.x;
    const int t = threadIdx.x;
    if (blk >= 256) {
        const int n1 = INNER * NDIM / 4;
        int i = (blk - 256) * 256 + t;
        const float* src; unsigned short* dst; int j;
        if (i < n1) { src = wq; dst = wqb; j = i; }
        else        { src = wo; dst = wob; j = i - n1; }
        float4 v = ((const float4*)src)[j];
        ushort4 u;
        u.x = f2bs(v.x); u.y = f2bs(v.y); u.z = f2bs(v.z); u.w = f2bs(v.w);
        ((ushort4*)dst)[j] = u;
        return;
    }
    __shared__ float ssum[8][32];
    __shared__ float ssq[8][32];
    __shared__ float mean_s[32];
    __shared__ float rstd_s[32];
    __shared__ unsigned short tile[32][72];

    const int b = blk >> 5;
    const int n0 = (blk & 31) * 32;
    {
        const int ln = t & 31, cg = t >> 5;
        const float* xp = x + (size_t)b * NDIM * NPOS + n0 + ln;
        float s = 0.f, ss = 0.f;
#pragma unroll 8
        for (int c = cg * 64; c < cg * 64 + 64; ++c) {
            float v = xp[(size_t)c * NPOS];
            s += v; ss += v * v;
        }
        ssum[cg][ln] = s; ssq[cg][ln] = ss;
    }
    __syncthreads();
    if (t < 32) {
        float st = 0.f, sq = 0.f;
#pragma unroll
        for (int g = 0; g < 8; ++g) { st += ssum[g][t]; sq += ssq[g][t]; }
        float m = st * (1.0f / NDIM);
        float var = sq * (1.0f / NDIM) - m * m;
        mean_s[t] = m;
        rstd_s[t] = rsqrtf(var + 1e-5f);
    }
    __syncthreads();

    const int cl = t >> 2, nq = (t & 3) * 8;
    const int nr = t >> 3, ch = (t & 7) * 8;
    for (int c0 = 0; c0 < NDIM; c0 += 64) {
        const float g = gamma[c0 + cl];
        const float* xp = x + ((size_t)b * NDIM + c0 + cl) * NPOS + n0 + nq;
        float4 v0 = *(const float4*)(xp);
        float4 v1 = *(const float4*)(xp + 4);
        float4 m0 = *(const float4*)&mean_s[nq];
        float4 m1 = *(const float4*)&mean_s[nq + 4];
        float4 r0 = *(const float4*)&rstd_s[nq];
        float4 r1 = *(const float4*)&rstd_s[nq + 4];
        tile[nq + 0][cl] = f2bs((v0.x - m0.x) * r0.x * g);
        tile[nq + 1][cl] = f2bs((v0.y - m0.y) * r0.y * g);
        tile[nq + 2][cl] = f2bs((v0.z - m0.z) * r0.z * g);
        tile[nq + 3][cl] = f2bs((v0.w - m0.w) * r0.w * g);
        tile[nq + 4][cl] = f2bs((v1.x - m1.x) * r1.x * g);
        tile[nq + 5][cl] = f2bs((v1.y - m1.y) * r1.y * g);
        tile[nq + 6][cl] = f2bs((v1.z - m1.z) * r1.z * g);
        tile[nq + 7][cl] = f2bs((v1.w - m1.w) * r1.w * g);
        __syncthreads();
        unsigned short* dst = xnT + ((size_t)b * NPOS + n0 + nr) * NDIM + c0 + ch;
        *(uint4*)dst = *(const uint4*)&tile[nr][ch];
        __syncthreads();
    }
}

__global__ __launch_bounds__(256) void qkv_mfma_kernel(
    const unsigned short* __restrict__ wq, const unsigned short* __restrict__ xnT,
    unsigned short* __restrict__ qT, unsigned short* __restrict__ kT,
    unsigned short* __restrict__ vv)
{
    __shared__ __align__(16) unsigned short smem[4 * 64 * 72];

    const int b = blockIdx.z;
    const int m0 = blockIdx.y * 128, n0 = blockIdx.x * 128;
    const int t = threadIdx.x, w = t >> 6, lane = t & 63;
    const int l15 = lane & 15, quad = lane >> 4;
    const int wm = (w >> 1) * 64, wn = (w & 1) * 64;
    const unsigned short* Abase = wq + (size_t)m0 * NDIM;
    const unsigned short* Bbase = xnT + ((size_t)b * NPOS + n0) * NDIM;

    const int rl = lane >> 2, sl = lane & 3;
    const int cw = (sl ^ ((rl >> 1) & 3)) * 8;
    const int sA = (quad ^ ((l15 >> 1) & 3)) * 8;

    f4v acc[4][4];
#pragma unroll
    for (int i = 0; i < 4; ++i)
#pragma unroll
        for (int j = 0; j < 4; ++j) { acc[i][j][0]=0.f; acc[i][j][1]=0.f; acc[i][j][2]=0.f; acc[i][j][3]=0.f; }

#pragma unroll
    for (int e = 0; e < 2; ++e) {
        const int seg = w * 2 + e;
        const int r = seg * 16 + rl;
        gl_lds16(Abase + (size_t)r * NDIM + cw, smem + seg * 512);
        gl_lds16(Bbase + (size_t)r * NDIM + cw, smem + 4096 + seg * 512);
    }

    for (int k0 = 0; k0 < NDIM; k0 += 32) {
        const int cur = (k0 >> 5) & 1;
        unsigned short* At = smem + cur * 8192;
        unsigned short* Bt = At + 4096;
        __syncthreads();
        if (k0 + 32 < NDIM) {
            unsigned short* An = smem + (cur ^ 1) * 8192;
#pragma unroll
            for (int e = 0; e < 2; ++e) {
                const int seg = w * 2 + e;
                const int r = seg * 16 + rl;
                gl_lds16(Abase + (size_t)r * NDIM + k0 + 32 + cw, An + seg * 512);
                gl_lds16(Bbase + (size_t)r * NDIM + k0 + 32 + cw, An + 4096 + seg * 512);
            }
        }
        bf8v af[4], bfr[4];
#pragma unroll
        for (int ms = 0; ms < 4; ++ms) af[ms]  = *(const bf8v*)&At[(wm + ms * 16 + l15) * 32 + sA];
#pragma unroll
        for (int ns = 0; ns < 4; ++ns) bfr[ns] = *(const bf8v*)&Bt[(wn + ns * 16 + l15) * 32 + sA];
#pragma unroll
        for (int ms = 0; ms < 4; ++ms)
#pragma unroll
            for (int ns = 0; ns < 4; ++ns)
                acc[ms][ns] = mfma16(af[ms], bfr[ns], acc[ms][ns]);
    }
    __syncthreads();

    const int sec = m0 >> 9;
    const int om  = m0 & 511;
    if (sec == 2) {
        unsigned short (*bw)[72] = (unsigned short(*)[72])(smem + w * 64 * 72);
        unsigned short* vbase = vv + ((size_t)b * NDIM + om) * NPOS + n0;
#pragma unroll
        for (int ms = 0; ms < 4; ++ms)
#pragma unroll
            for (int ns = 0; ns < 4; ++ns)
#pragma unroll
                for (int r = 0; r < 4; ++r)
                    bw[ms * 16 + quad * 4 + r][ns * 16 + l15] = f2bs(acc[ms][ns][r]);
#pragma unroll
        for (int r2 = 0; r2 < 4; ++r2) {
            const int ml = r2 * 16 + (lane >> 2);
            unsigned short* dstr = vbase + (size_t)(wm + ml) * NPOS + wn + (lane & 3) * 8;
            *(uint4*)dstr        = *(const uint4*)&bw[ml][(lane & 3) * 8];
            *(uint4*)(dstr + 32) = *(const uint4*)&bw[ml][32 + (lane & 3) * 8];
        }
    } else {
        const float qsc = (sec == 0) ? 0.18033688f : 1.0f;
        unsigned short* gT = (sec == 0 ? qT : kT) + ((size_t)b * NPOS + n0) * NDIM + om;
        unsigned short (*bw)[72] = (unsigned short(*)[72])(smem + w * 64 * 72);
#pragma unroll
        for (int ms = 0; ms < 4; ++ms)
#pragma unroll
            for (int ns = 0; ns < 4; ++ns)
#pragma unroll
                for (int r = 0; r < 4; ++r)
                    bw[ns * 16 + l15][ms * 16 + quad * 4 + r] = f2bs(acc[ms][ns][r] * qsc);
#pragma unroll
        for (int r2 = 0; r2 < 4; ++r2) {
            const int nl = r2 * 16 + (lane >> 2);
            unsigned short* dstr = gT + (size_t)(wn + nl) * NDIM + wm + (lane & 3) * 8;
            *(uint4*)dstr        = *(const uint4*)&bw[nl][(lane & 3) * 8];
            *(uint4*)(dstr + 32) = *(const uint4*)&bw[nl][32 + (lane & 3) * 8];
        }
    }
}

__global__ __launch_bounds__(256, 2) void attn_mfma8_kernel(
    const unsigned short* __restrict__ qT, const unsigned short* __restrict__ kT,
    const unsigned short* __restrict__ vv, unsigned short* __restrict__ attnT)
{
    __shared__ __align__(16) unsigned short Kb[2][4096];
    __shared__ __align__(16) unsigned short Vb[2][4096];
    __shared__ __align__(16) unsigned short Ps[4][32][72];

    const int blk = blockIdx.x;
    const int xg = blk & 7, rr = blk >> 3;
    const int i0 = (rr & 7) * 128;
    const int bh = ((rr >> 3) << 3) | xg;
    const int b = bh >> 3, h = bh & 7;

    const int t = threadIdx.x, w = t >> 6, lane = t & 63;
    const int l15 = lane & 15, quad = lane >> 4;

    const unsigned short* kbase = kT + (size_t)b * NPOS * NDIM + h * DHEAD;
    const unsigned short* vbase = vv + ((size_t)b * NDIM + h * DHEAD) * NPOS;

    bf8v bq[2][2];
#pragma unroll
    for (int g = 0; g < 2; ++g) {
        const unsigned short* qrow =
            qT + ((size_t)b * NPOS + i0 + w * 32 + g * 16 + l15) * NDIM + h * DHEAD;
        bq[g][0] = *(const bf8v*)(qrow + quad * 8);
        bq[g][1] = *(const bf8v*)(qrow + 32 + quad * 8);
    }

    bf8v bones;
#pragma unroll
    for (int e = 0; e < 8; ++e) bones[e] = (short)0x3F80;

    const int rloc = lane >> 3;
    const int gch = ((lane & 7) ^ (rloc & 7)) * 8;
    const int sw0 = (quad ^ (l15 & 7)) * 8;
    const int sw1 = ((4 + quad) ^ (l15 & 7)) * 8;

#pragma unroll
    for (int e = 0; e < 2; ++e) {
        const int seg = w * 2 + e;
        const int row = seg * 8 + rloc;
        gl_lds16(kbase + (size_t)row * NDIM + gch, &Kb[0][seg * 512]);
        gl_lds16(vbase + (size_t)row * NPOS + gch, &Vb[0][seg * 512]);
    }

    f4v oc[2][5];
#pragma unroll
    for (int mg = 0; mg < 2; ++mg)
#pragma unroll
        for (int cs = 0; cs < 5; ++cs) { oc[mg][cs][0]=0.f; oc[mg][cs][1]=0.f; oc[mg][cs][2]=0.f; oc[mg][cs][3]=0.f; }

#pragma unroll 2
    for (int j0 = 0; j0 < NPOS; j0 += 64) {
        const int cur = (j0 >> 6) & 1, nxt = cur ^ 1;
        __syncthreads();
        if (j0 + 64 < NPOS) {
#pragma unroll
            for (int e = 0; e < 2; ++e) {
                const int seg = w * 2 + e;
                const int row = seg * 8 + rloc;
                gl_lds16(kbase + (size_t)(j0 + 64 + row) * NDIM + gch, &Kb[nxt][seg * 512]);
                gl_lds16(vbase + (size_t)row * NPOS + j0 + 64 + gch, &Vb[nxt][seg * 512]);
            }
        }

        f4v sacc[4][2];
        __builtin_amdgcn_s_setprio(1);
#pragma unroll
        for (int jt = 0; jt < 4; ++jt) {
            const int krow = (jt * 16 + l15) * 64;
            bf8v ak0 = *(const bf8v*)&Kb[cur][krow + sw0];
            bf8v ak1 = *(const bf8v*)&Kb[cur][krow + sw1];
#pragma unroll
            for (int g = 0; g < 2; ++g) {
                f4v s; s[0]=0.f; s[1]=0.f; s[2]=0.f; s[3]=0.f;
                s = mfma16(ak0, bq[g][0], s);
                sacc[jt][g] = mfma16(ak1, bq[g][1], s);
            }
        }
        __builtin_amdgcn_s_setprio(0);

#pragma unroll
        for (int jt = 0; jt < 4; ++jt)
#pragma unroll
            for (int g = 0; g < 2; ++g) {
                ushort4 pu;
                pu.x = f2bs(__builtin_amdgcn_exp2f(sacc[jt][g][0]));
                pu.y = f2bs(__builtin_amdgcn_exp2f(sacc[jt][g][1]));
                pu.z = f2bs(__builtin_amdgcn_exp2f(sacc[jt][g][2]));
                pu.w = f2bs(__builtin_amdgcn_exp2f(sacc[jt][g][3]));
                *(ushort4*)&Ps[w][g * 16 + l15][jt * 16 + quad * 4] = pu;
            }

        bf8v ap[2][2];
#pragma unroll
        for (int mg = 0; mg < 2; ++mg) {
            ap[mg][0] = *(const bf8v*)&Ps[w][mg * 16 + l15][quad * 8];
            ap[mg][1] = *(const bf8v*)&Ps[w][mg * 16 + l15][32 + quad * 8];
        }
        __builtin_amdgcn_s_setprio(1);
#pragma unroll
        for (int cs = 0; cs < 4; ++cs) {
            const int vrow = (cs * 16 + l15) * 64;
            bf8v bv0 = *(const bf8v*)&Vb[cur][vrow + sw0];
            bf8v bv1 = *(const bf8v*)&Vb[cur][vrow + sw1];
#pragma unroll
            for (int mg = 0; mg < 2; ++mg) {
                oc[mg][cs] = mfma16(ap[mg][0], bv0, oc[mg][cs]);
                oc[mg][cs] = mfma16(ap[mg][1], bv1, oc[mg][cs]);
            }
        }
#pragma unroll
        for (int mg = 0; mg < 2; ++mg) {
            oc[mg][4] = mfma16(ap[mg][0], bones, oc[mg][4]);
            oc[mg][4] = mfma16(ap[mg][1], bones, oc[mg][4]);
        }
        __builtin_amdgcn_s_setprio(0);
    }

#pragma unroll
    for (int mg = 0; mg < 2; ++mg) {
        float inv[4];
#pragma unroll
        for (int r = 0; r < 4; ++r) inv[r] = __builtin_amdgcn_rcpf(oc[mg][4][r]);
#pragma unroll
        for (int cs = 0; cs < 4; ++cs)
#pragma unroll
            for (int r = 0; r < 4; ++r)
                Ps[w][mg * 16 + quad * 4 + r][cs * 16 + l15] = f2bs(oc[mg][cs][r] * inv[r]);
    }
    {
        const int br = lane >> 1;
        const int bc = lane & 1;
        unsigned short* dst =
            attnT + ((size_t)b * NPOS + i0 + w * 32 + br) * NDIM + h * DHEAD;
#pragma unroll
        for (int q2 = 0; q2 < 4; ++q2)
            *(uint4*)(dst + (q2 * 2 + bc) * 8) = *(const uint4*)&Ps[w][br][(q2 * 2 + bc) * 8];
    }
}

__global__ __launch_bounds__(256) void out_mfma_kernel(
    const unsigned short* __restrict__ wo, const unsigned short* __restrict__ attnT,
    const float* __restrict__ x, float* __restrict__ outp)
{
    __shared__ __align__(16) unsigned short smem[12288];

    const int b = blockIdx.z;
    const int m0 = blockIdx.y * 64, n0 = blockIdx.x * 128;
    const int t = threadIdx.x, w = t >> 6, lane = t & 63;
    const int l15 = lane & 15, quad = lane >> 4;
    const int wm = (w >> 1) * 32, wn = (w & 1) * 64;
    const unsigned short* Abase = wo + (size_t)m0 * NDIM;
    const unsigned short* Bbase = attnT + ((size_t)b * NPOS + n0) * NDIM;

    const int rl = lane >> 2, sl = lane & 3;
    const int cw = (sl ^ ((rl >> 1) & 3)) * 8;
    const int sA = (quad ^ ((l15 >> 1) & 3)) * 8;

    f4v acc[2][4];
#pragma unroll
    for (int i = 0; i < 2; ++i)
#pragma unroll
        for (int j = 0; j < 4; ++j) { acc[i][j][0]=0.f; acc[i][j][1]=0.f; acc[i][j][2]=0.f; acc[i][j][3]=0.f; }

    {
        const int r = w * 16 + rl;
        gl_lds16(Abase + (size_t)r * NDIM + cw, smem + w * 512);
#pragma unroll
        for (int e = 0; e < 2; ++e) {
            const int seg = w * 2 + e;
            const int rb = seg * 16 + rl;
            gl_lds16(Bbase + (size_t)rb * NDIM + cw, smem + 2048 + seg * 512);
        }
    }

    for (int k0 = 0; k0 < NDIM; k0 += 32) {
        const int cur = (k0 >> 5) & 1;
        unsigned short* At = smem + cur * 6144;
        unsigned short* Bt = At + 2048;
        __syncthreads();
        if (k0 + 32 < NDIM) {
            unsigned short* An = smem + (cur ^ 1) * 6144;
            const int r = w * 16 + rl;
            gl_lds16(Abase + (size_t)r * NDIM + k0 + 32 + cw, An + w * 512);
#pragma unroll
            for (int e = 0; e < 2; ++e) {
                const int seg = w * 2 + e;
                const int rb = seg * 16 + rl;
                gl_lds16(Bbase + (size_t)rb * NDIM + k0 + 32 + cw, An + 2048 + seg * 512);
            }
        }
        bf8v af[2], bfr[4];
#pragma unroll
        for (int ms = 0; ms < 2; ++ms) af[ms]  = *(const bf8v*)&At[(wm + ms * 16 + l15) * 32 + sA];
#pragma unroll
        for (int ns = 0; ns < 4; ++ns) bfr[ns] = *(const bf8v*)&Bt[(wn + ns * 16 + l15) * 32 + sA];
#pragma unroll
        for (int ms = 0; ms < 2; ++ms)
#pragma unroll
            for (int ns = 0; ns < 4; ++ns)
                acc[ms][ns] = mfma16(af[ms], bfr[ns], acc[ms][ns]);
    }
    const float* xb = x + ((size_t)b * NDIM + m0) * NPOS + n0;
    float* ob = outp + ((size_t)b * NDIM + m0) * NPOS + n0;
#pragma unroll
    for (int ms = 0; ms < 2; ++ms)
#pragma unroll
        for (int r = 0; r < 4; ++r) {
            int m = wm + ms * 16 + quad * 4 + r;
#pragma unroll
            for (int ns = 0; ns < 4; ++ns) {
                int n = wn + ns * 16 + l15;
                ob[(size_t)m * NPOS + n] = acc[ms][ns][r] + xb[(size_t)m * NPOS + n];
            }
        }
}

extern "C" void kernel_launch(void* const* d_in, const int* in_sizes, int n_in,
                              void* d_out, int out_size, void* d_ws, size_t ws_size,
                              hipStream_t stream) {
    const float* x     = (const float*)d_in[0];   // [8][512][32][32] f32
    const float* gamma = (const float*)d_in[1];   // [512] f32
    const float* w_qkv = (const float*)d_in[2];   // [1536][512] f32
    const float* w_out = (const float*)d_in[3];   // [512][512] f32
    float* out = (float*)d_out;                   // [8][512][32][32] f32

    unsigned short* xnT = (unsigned short*)d_ws;             // 8*1024*512 bf16
    unsigned short* wqb = xnT + (size_t)NB * NPOS * NDIM;    // 1536*512
    unsigned short* wob = wqb + (size_t)INNER * NDIM;        // 512*512
    unsigned short* qTw = wob + (size_t)NDIM * NDIM;         // 8*1024*512
    unsigned short* kTw = qTw + (size_t)NB * NPOS * NDIM;
    unsigned short* vvw = kTw + (size_t)NB * NPOS * NDIM;
    unsigned short* aTw = vvw + (size_t)NB * NPOS * NDIM;

    void* args[] = {
        (void*)&x, (void*)&gamma, (void*)&w_qkv, (void*)&w_out,
        (void*)&xnT, (void*)&wqb, (void*)&wob, (void*)&qTw,
        (void*)&kTw, (void*)&vvw, (void*)&aTw, (void*)&out };
    hipError_t err = hipLaunchCooperativeKernel(
        mega_kernel, dim3(512), dim3(256), args, 0, stream);
    if (err != hipSuccess) {
        // fallback: original 4-kernel chain
        prep_kernel<<<256 + (INNER * NDIM + NDIM * NDIM) / 4 / 256, 256, 0, stream>>>(
            x, gamma, w_qkv, w_out, xnT, wqb, wob);
        qkv_mfma_kernel<<<dim3(NPOS / 128, INNER / 128, NB), 256, 0, stream>>>(
            wqb, xnT, qTw, kTw, vvw);
        attn_mfma8_kernel<<<512, 256, 0, stream>>>(qTw, kTw, vvw, aTw);
        out_mfma_kernel<<<dim3(NPOS / 128, NDIM / 64, NB), 256, 0, stream>>>(wob, aTw, x, out);
    }
}

// Round 4
// 132.118 us; speedup vs baseline: 2.4756x; 2.4756x over previous
//
#include <hip/hip_runtime.h>
#include <hip/hip_bf16.h>

#define NDIM   512
#define NPOS   1024   // 32*32
#define NB     8
#define INNER  1536
#define DHEAD  64

typedef __attribute__((ext_vector_type(8))) short bf8v;   // 8 bf16 = 4 VGPRs
typedef __attribute__((ext_vector_type(4))) float f4v;

__device__ __forceinline__ f4v mfma16(bf8v a, bf8v b, f4v c) {
    return __builtin_amdgcn_mfma_f32_16x16x32_bf16(a, b, c, 0, 0, 0);
}

__device__ __forceinline__ unsigned short f2bs(float v) {
    __hip_bfloat16 h = __float2bfloat16(v);   // RNE
    return *reinterpret_cast<unsigned short*>(&h);
}

// async global->LDS, 16B per lane; lds dst = wave-uniform base + lane*16
__device__ __forceinline__ void gl_lds16(const unsigned short* g, unsigned short* l) {
    __builtin_amdgcn_global_load_lds(
        (const __attribute__((address_space(1))) void*)g,
        (__attribute__((address_space(3))) void*)l,
        16, 0, 0);
}

// ---------------- K1: fused prep = LN+transpose (blocks 0..255) -----------
//                    + weight bf16 cast (blocks 256..1279)
__global__ __launch_bounds__(256) void prep_kernel(
    const float* __restrict__ x, const float* __restrict__ gamma,
    const float* __restrict__ wq, const float* __restrict__ wo,
    unsigned short* __restrict__ xnT, unsigned short* __restrict__ wqb,
    unsigned short* __restrict__ wob)
{
    const int blk = blockIdx.x;
    const int t = threadIdx.x;
    if (blk >= 256) {
        // ---- weight cast: 262144 float4 groups over 1024 blocks ----
        const int n1 = INNER * NDIM / 4;
        int i = (blk - 256) * 256 + t;
        const float* src; unsigned short* dst; int j;
        if (i < n1) { src = wq; dst = wqb; j = i; }
        else        { src = wo; dst = wob; j = i - n1; }
        float4 v = ((const float4*)src)[j];
        ushort4 u;
        u.x = f2bs(v.x); u.y = f2bs(v.y); u.z = f2bs(v.z); u.w = f2bs(v.w);
        ((ushort4*)dst)[j] = u;
        return;
    }
    // ---- LN stats + normalize + cast + transpose (32 positions/block) ----
    __shared__ float ssum[8][32];
    __shared__ float ssq[8][32];
    __shared__ float mean_s[32];
    __shared__ float rstd_s[32];
    __shared__ unsigned short tile[32][72];

    const int b = blk >> 5;
    const int n0 = (blk & 31) * 32;
    {
        const int ln = t & 31, cg = t >> 5;   // 8 channel-groups x 64 channels
        const float* xp = x + (size_t)b * NDIM * NPOS + n0 + ln;
        float s = 0.f, ss = 0.f;
#pragma unroll 8
        for (int c = cg * 64; c < cg * 64 + 64; ++c) {
            float v = xp[(size_t)c * NPOS];
            s += v; ss += v * v;
        }
        ssum[cg][ln] = s; ssq[cg][ln] = ss;
    }
    __syncthreads();
    if (t < 32) {
        float st = 0.f, sq = 0.f;
#pragma unroll
        for (int g = 0; g < 8; ++g) { st += ssum[g][t]; sq += ssq[g][t]; }
        float m = st * (1.0f / NDIM);
        float var = sq * (1.0f / NDIM) - m * m;
        mean_s[t] = m;
        rstd_s[t] = rsqrtf(var + 1e-5f);
    }
    __syncthreads();

    const int cl = t >> 2, nq = (t & 3) * 8;   // load/normalize indexing
    const int nr = t >> 3, ch = (t & 7) * 8;   // store indexing
    for (int c0 = 0; c0 < NDIM; c0 += 64) {
        const float g = gamma[c0 + cl];
        const float* xp = x + ((size_t)b * NDIM + c0 + cl) * NPOS + n0 + nq;
        float4 v0 = *(const float4*)(xp);
        float4 v1 = *(const float4*)(xp + 4);
        float4 m0 = *(const float4*)&mean_s[nq];
        float4 m1 = *(const float4*)&mean_s[nq + 4];
        float4 r0 = *(const float4*)&rstd_s[nq];
        float4 r1 = *(const float4*)&rstd_s[nq + 4];
        tile[nq + 0][cl] = f2bs((v0.x - m0.x) * r0.x * g);
        tile[nq + 1][cl] = f2bs((v0.y - m0.y) * r0.y * g);
        tile[nq + 2][cl] = f2bs((v0.z - m0.z) * r0.z * g);
        tile[nq + 3][cl] = f2bs((v0.w - m0.w) * r0.w * g);
        tile[nq + 4][cl] = f2bs((v1.x - m1.x) * r1.x * g);
        tile[nq + 5][cl] = f2bs((v1.y - m1.y) * r1.y * g);
        tile[nq + 6][cl] = f2bs((v1.z - m1.z) * r1.z * g);
        tile[nq + 7][cl] = f2bs((v1.w - m1.w) * r1.w * g);
        __syncthreads();
        unsigned short* dst = xnT + ((size_t)b * NPOS + n0 + nr) * NDIM + c0 + ch;
        *(uint4*)dst = *(const uint4*)&tile[nr][ch];
        __syncthreads();
    }
}

// ---------------- K2: QKV GEMM (3-buf counted-vmcnt pipeline) -------------
__global__ __launch_bounds__(256) void qkv_mfma_kernel(
    const unsigned short* __restrict__ wq, const unsigned short* __restrict__ xnT,
    unsigned short* __restrict__ qT, unsigned short* __restrict__ kT,
    unsigned short* __restrict__ vv)
{
    // buf i at smem + i*8192 shorts (A 4096 + B 4096); DMA runs 2 tiles ahead.
    __shared__ __align__(16) unsigned short smem[3 * 8192];   // 49152 B

    const int b = blockIdx.z;
    const int m0 = blockIdx.y * 128, n0 = blockIdx.x * 128;
    const int t = threadIdx.x, w = t >> 6, lane = t & 63;
    const int l15 = lane & 15, quad = lane >> 4;
    const int wm = (w >> 1) * 64, wn = (w & 1) * 64;
    const unsigned short* Abase = wq + (size_t)m0 * NDIM;
    const unsigned short* Bbase = xnT + ((size_t)b * NPOS + n0) * NDIM;

    const int rl = lane >> 2, sl = lane & 3;
    const int cw = (sl ^ ((rl >> 1) & 3)) * 8;      // write-side global chunk offset
    const int sA = (quad ^ ((l15 >> 1) & 3)) * 8;   // read-side LDS slot offset

    f4v acc[4][4];
#pragma unroll
    for (int i = 0; i < 4; ++i)
#pragma unroll
        for (int j = 0; j < 4; ++j) { acc[i][j][0]=0.f; acc[i][j][1]=0.f; acc[i][j][2]=0.f; acc[i][j][3]=0.f; }

    auto STAGE = [&](int k0, unsigned short* buf) {   // 4 DMA loads per thread
#pragma unroll
        for (int e = 0; e < 2; ++e) {
            const int seg = w * 2 + e;                  // 0..7, 16 rows each
            const int r = seg * 16 + rl;
            gl_lds16(Abase + (size_t)r * NDIM + k0 + cw, buf + seg * 512);
            gl_lds16(Bbase + (size_t)r * NDIM + k0 + cw, buf + 4096 + seg * 512);
        }
    };

    // prologue: tiles 0,1 in flight (8 outstanding loads/wave)
    STAGE(0, smem);
    STAGE(32, smem + 8192);

#pragma unroll
    for (int kt = 0; kt < 16; ++kt) {
        // wait tile kt complete; tile kt+1's 4 loads may stay in flight
        if (kt < 15) asm volatile("s_waitcnt vmcnt(4)" ::: "memory");
        else         asm volatile("s_waitcnt vmcnt(0)" ::: "memory");
        __builtin_amdgcn_sched_barrier(0);
        __builtin_amdgcn_s_barrier();   // all waves: tile kt ready, prev reads done
        __builtin_amdgcn_sched_barrier(0);
        if (kt + 2 < 16) STAGE((kt + 2) * 32, smem + ((kt + 2) % 3) * 8192);
        unsigned short* At = smem + (kt % 3) * 8192;
        unsigned short* Bt = At + 4096;
        bf8v af[4], bfr[4];
#pragma unroll
        for (int ms = 0; ms < 4; ++ms) af[ms]  = *(const bf8v*)&At[(wm + ms * 16 + l15) * 32 + sA];
#pragma unroll
        for (int ns = 0; ns < 4; ++ns) bfr[ns] = *(const bf8v*)&Bt[(wn + ns * 16 + l15) * 32 + sA];
#pragma unroll
        for (int ms = 0; ms < 4; ++ms)
#pragma unroll
            for (int ns = 0; ns < 4; ++ns)
                acc[ms][ns] = mfma16(af[ms], bfr[ns], acc[ms][ns]);
    }
    __syncthreads();   // done with bufs; smem reusable as bounce

    const int sec = m0 >> 9;         // 0=q, 1=k, 2=v
    const int om  = m0 & 511;
    if (sec == 2) {
        // V epilogue: bounce through LDS [m][n], then 64B-contiguous vector stores
        unsigned short (*bw)[72] = (unsigned short(*)[72])(smem + w * 64 * 72);
        unsigned short* vbase = vv + ((size_t)b * NDIM + om) * NPOS + n0;
#pragma unroll
        for (int ms = 0; ms < 4; ++ms)
#pragma unroll
            for (int ns = 0; ns < 4; ++ns)
#pragma unroll
                for (int r = 0; r < 4; ++r)
                    bw[ms * 16 + quad * 4 + r][ns * 16 + l15] = f2bs(acc[ms][ns][r]);
#pragma unroll
        for (int r2 = 0; r2 < 4; ++r2) {
            const int ml = r2 * 16 + (lane >> 2);
            unsigned short* dstr = vbase + (size_t)(wm + ml) * NPOS + wn + (lane & 3) * 8;
            *(uint4*)dstr        = *(const uint4*)&bw[ml][(lane & 3) * 8];
            *(uint4*)(dstr + 32) = *(const uint4*)&bw[ml][32 + (lane & 3) * 8];
        }
    } else {
        // fold dim_head^-0.5 AND log2(e) into Q: attn uses exp2 directly
        const float qsc = (sec == 0) ? 0.18033688f : 1.0f;   // 0.125 * 1.4426950
        unsigned short* gT = (sec == 0 ? qT : kT) + ((size_t)b * NPOS + n0) * NDIM + om;
        unsigned short (*bw)[72] = (unsigned short(*)[72])(smem + w * 64 * 72);
#pragma unroll
        for (int ms = 0; ms < 4; ++ms)
#pragma unroll
            for (int ns = 0; ns < 4; ++ns)
#pragma unroll
                for (int r = 0; r < 4; ++r)
                    bw[ns * 16 + l15][ms * 16 + quad * 4 + r] = f2bs(acc[ms][ns][r] * qsc);
#pragma unroll
        for (int r2 = 0; r2 < 4; ++r2) {
            const int nl = r2 * 16 + (lane >> 2);
            unsigned short* dstr = gT + (size_t)(wn + nl) * NDIM + wm + (lane & 3) * 8;
            *(uint4*)dstr        = *(const uint4*)&bw[nl][(lane & 3) * 8];
            *(uint4*)(dstr + 32) = *(const uint4*)&bw[nl][32 + (lane & 3) * 8];
        }
    }
}

// ---------------- K3: flash attention v9 (phase-split MFMA/exp/PV) --------
__global__ __launch_bounds__(256, 2) void attn_mfma8_kernel(
    const unsigned short* __restrict__ qT, const unsigned short* __restrict__ kT,
    const unsigned short* __restrict__ vv, unsigned short* __restrict__ attnT)
{
    __shared__ __align__(16) unsigned short Kb[2][4096];     // [j][c] 64x64, swizzled
    __shared__ __align__(16) unsigned short Vb[2][4096];     // [c][j] 64x64, swizzled
    __shared__ __align__(16) unsigned short Ps[4][32][72];   // wave-private stripes

    // XCD swizzle: blk&7 = h; per-XCD K/V working set 2MB < 4MB L2.
    const int blk = blockIdx.x;                 // 512 blocks
    const int xg = blk & 7, rr = blk >> 3;
    const int i0 = (rr & 7) * 128;
    const int bh = ((rr >> 3) << 3) | xg;
    const int b = bh >> 3, h = bh & 7;

    const int t = threadIdx.x, w = t >> 6, lane = t & 63;
    const int l15 = lane & 15, quad = lane >> 4;

    const unsigned short* kbase = kT + (size_t)b * NPOS * NDIM + h * DHEAD;   // row j, stride NDIM
    const unsigned short* vbase = vv + ((size_t)b * NDIM + h * DHEAD) * NPOS; // row c, stride NPOS

    bf8v bq[2][2];
#pragma unroll
    for (int g = 0; g < 2; ++g) {
        const unsigned short* qrow =
            qT + ((size_t)b * NPOS + i0 + w * 32 + g * 16 + l15) * NDIM + h * DHEAD;
        bq[g][0] = *(const bf8v*)(qrow + quad * 8);
        bq[g][1] = *(const bf8v*)(qrow + 32 + quad * 8);
    }

    bf8v bones;   // constant ones fragment: l = sum_j P[i][j]
#pragma unroll
    for (int e = 0; e < 8; ++e) bones[e] = (short)0x3F80;

    const int rloc = lane >> 3;
    const int gch = ((lane & 7) ^ (rloc & 7)) * 8;   // global chunk offset (shorts)
    const int sw0 = (quad ^ (l15 & 7)) * 8;          // chunks 0..3 (c/j 0..31)
    const int sw1 = ((4 + quad) ^ (l15 & 7)) * 8;    // chunks 4..7 (c/j 32..63)

    // prologue: stage tile 0 into buffer 0
#pragma unroll
    for (int e = 0; e < 2; ++e) {
        const int seg = w * 2 + e;                   // 0..7
        const int row = seg * 8 + rloc;
        gl_lds16(kbase + (size_t)row * NDIM + gch, &Kb[0][seg * 512]);
        gl_lds16(vbase + (size_t)row * NPOS + gch, &Vb[0][seg * 512]);
    }

    f4v oc[2][5];
#pragma unroll
    for (int mg = 0; mg < 2; ++mg)
#pragma unroll
        for (int cs = 0; cs < 5; ++cs) { oc[mg][cs][0]=0.f; oc[mg][cs][1]=0.f; oc[mg][cs][2]=0.f; oc[mg][cs][3]=0.f; }

#pragma unroll 2
    for (int j0 = 0; j0 < NPOS; j0 += 64) {
        const int cur = (j0 >> 6) & 1, nxt = cur ^ 1;
        __syncthreads();   // vmcnt(0) drain: tile-cur DMA done; reads of nxt done
        if (j0 + 64 < NPOS) {
#pragma unroll
            for (int e = 0; e < 2; ++e) {
                const int seg = w * 2 + e;
                const int row = seg * 8 + rloc;
                gl_lds16(kbase + (size_t)(j0 + 64 + row) * NDIM + gch, &Kb[nxt][seg * 512]);
                gl_lds16(vbase + (size_t)row * NPOS + j0 + 64 + gch, &Vb[nxt][seg * 512]);
            }
        }

        // ---- phase A: all 16 QK^T MFMAs (matrix pipe saturates) ----
        f4v sacc[4][2];
        __builtin_amdgcn_s_setprio(1);
#pragma unroll
        for (int jt = 0; jt < 4; ++jt) {
            const int krow = (jt * 16 + l15) * 64;
            bf8v ak0 = *(const bf8v*)&Kb[cur][krow + sw0];
            bf8v ak1 = *(const bf8v*)&Kb[cur][krow + sw1];
#pragma unroll
            for (int g = 0; g < 2; ++g) {
                f4v s; s[0]=0.f; s[1]=0.f; s[2]=0.f; s[3]=0.f;
                s = mfma16(ak0, bq[g][0], s);
                sacc[jt][g] = mfma16(ak1, bq[g][1], s);
            }
        }
        __builtin_amdgcn_s_setprio(0);

        // ---- phase B: batch exp2 + pack + Ps write (trans/VALU pipe) ----
#pragma unroll
        for (int jt = 0; jt < 4; ++jt)
#pragma unroll
            for (int g = 0; g < 2; ++g) {
                ushort4 pu;
                pu.x = f2bs(__builtin_amdgcn_exp2f(sacc[jt][g][0]));
                pu.y = f2bs(__builtin_amdgcn_exp2f(sacc[jt][g][1]));
                pu.z = f2bs(__builtin_amdgcn_exp2f(sacc[jt][g][2]));
                pu.w = f2bs(__builtin_amdgcn_exp2f(sacc[jt][g][3]));
                *(ushort4*)&Ps[w][g * 16 + l15][jt * 16 + quad * 4] = pu;
            }

        // ---- phase C: PV MFMAs ----
        bf8v ap[2][2];
#pragma unroll
        for (int mg = 0; mg < 2; ++mg) {
            ap[mg][0] = *(const bf8v*)&Ps[w][mg * 16 + l15][quad * 8];
            ap[mg][1] = *(const bf8v*)&Ps[w][mg * 16 + l15][32 + quad * 8];
        }
        __builtin_amdgcn_s_setprio(1);
#pragma unroll
        for (int cs = 0; cs < 4; ++cs) {
            const int vrow = (cs * 16 + l15) * 64;
            bf8v bv0 = *(const bf8v*)&Vb[cur][vrow + sw0];
            bf8v bv1 = *(const bf8v*)&Vb[cur][vrow + sw1];
#pragma unroll
            for (int mg = 0; mg < 2; ++mg) {
                oc[mg][cs] = mfma16(ap[mg][0], bv0, oc[mg][cs]);
                oc[mg][cs] = mfma16(ap[mg][1], bv1, oc[mg][cs]);
            }
        }
#pragma unroll
        for (int mg = 0; mg < 2; ++mg) {
            oc[mg][4] = mfma16(ap[mg][0], bones, oc[mg][4]);
            oc[mg][4] = mfma16(ap[mg][1], bones, oc[mg][4]);
        }
        __builtin_amdgcn_s_setprio(0);
    }

    // epilogue: normalize, bounce through Ps[w] stripe, vector stores
#pragma unroll
    for (int mg = 0; mg < 2; ++mg) {
        float inv[4];
#pragma unroll
        for (int r = 0; r < 4; ++r) inv[r] = __builtin_amdgcn_rcpf(oc[mg][4][r]);
#pragma unroll
        for (int cs = 0; cs < 4; ++cs)
#pragma unroll
            for (int r = 0; r < 4; ++r)
                Ps[w][mg * 16 + quad * 4 + r][cs * 16 + l15] = f2bs(oc[mg][cs][r] * inv[r]);
    }
    {
        const int br = lane >> 1;            // 0..31 (row within wave's 32 q-rows)
        const int bc = lane & 1;             // chunk parity
        unsigned short* dst =
            attnT + ((size_t)b * NPOS + i0 + w * 32 + br) * NDIM + h * DHEAD;
#pragma unroll
        for (int q2 = 0; q2 < 4; ++q2)
            *(uint4*)(dst + (q2 * 2 + bc) * 8) = *(const uint4*)&Ps[w][br][(q2 * 2 + bc) * 8];
    }
}

// ---------------- K4: out projection (3-buf counted-vmcnt pipeline) -------
__global__ __launch_bounds__(256) void out_mfma_kernel(
    const unsigned short* __restrict__ wo, const unsigned short* __restrict__ attnT,
    const float* __restrict__ x, float* __restrict__ outp)
{
    // buf i at smem + i*6144 shorts (A 2048 + B 4096); DMA runs 2 tiles ahead.
    __shared__ __align__(16) unsigned short smem[3 * 6144];   // 36864 B

    const int b = blockIdx.z;
    const int m0 = blockIdx.y * 64, n0 = blockIdx.x * 128;
    const int t = threadIdx.x, w = t >> 6, lane = t & 63;
    const int l15 = lane & 15, quad = lane >> 4;
    const int wm = (w >> 1) * 32, wn = (w & 1) * 64;
    const unsigned short* Abase = wo + (size_t)m0 * NDIM;
    const unsigned short* Bbase = attnT + ((size_t)b * NPOS + n0) * NDIM;

    const int rl = lane >> 2, sl = lane & 3;
    const int cw = (sl ^ ((rl >> 1) & 3)) * 8;
    const int sA = (quad ^ ((l15 >> 1) & 3)) * 8;

    f4v acc[2][4];
#pragma unroll
    for (int i = 0; i < 2; ++i)
#pragma unroll
        for (int j = 0; j < 4; ++j) { acc[i][j][0]=0.f; acc[i][j][1]=0.f; acc[i][j][2]=0.f; acc[i][j][3]=0.f; }

    auto STAGE = [&](int k0, unsigned short* buf) {   // 3 DMA loads per thread
        const int r = w * 16 + rl;
        gl_lds16(Abase + (size_t)r * NDIM + k0 + cw, buf + w * 512);
#pragma unroll
        for (int e = 0; e < 2; ++e) {
            const int seg = w * 2 + e;
            const int rb = seg * 16 + rl;
            gl_lds16(Bbase + (size_t)rb * NDIM + k0 + cw, buf + 2048 + seg * 512);
        }
    };

    // prologue: tiles 0,1 in flight (6 outstanding loads/wave)
    STAGE(0, smem);
    STAGE(32, smem + 6144);

#pragma unroll
    for (int kt = 0; kt < 16; ++kt) {
        if (kt < 15) asm volatile("s_waitcnt vmcnt(3)" ::: "memory");
        else         asm volatile("s_waitcnt vmcnt(0)" ::: "memory");
        __builtin_amdgcn_sched_barrier(0);
        __builtin_amdgcn_s_barrier();
        __builtin_amdgcn_sched_barrier(0);
        if (kt + 2 < 16) STAGE((kt + 2) * 32, smem + ((kt + 2) % 3) * 6144);
        unsigned short* At = smem + (kt % 3) * 6144;
        unsigned short* Bt = At + 2048;
        bf8v af[2], bfr[4];
#pragma unroll
        for (int ms = 0; ms < 2; ++ms) af[ms]  = *(const bf8v*)&At[(wm + ms * 16 + l15) * 32 + sA];
#pragma unroll
        for (int ns = 0; ns < 4; ++ns) bfr[ns] = *(const bf8v*)&Bt[(wn + ns * 16 + l15) * 32 + sA];
#pragma unroll
        for (int ms = 0; ms < 2; ++ms)
#pragma unroll
            for (int ns = 0; ns < 4; ++ns)
                acc[ms][ns] = mfma16(af[ms], bfr[ns], acc[ms][ns]);
    }
    const float* xb = x + ((size_t)b * NDIM + m0) * NPOS + n0;
    float* ob = outp + ((size_t)b * NDIM + m0) * NPOS + n0;
#pragma unroll
    for (int ms = 0; ms < 2; ++ms)
#pragma unroll
        for (int r = 0; r < 4; ++r) {
            int m = wm + ms * 16 + quad * 4 + r;
#pragma unroll
            for (int ns = 0; ns < 4; ++ns) {
                int n = wn + ns * 16 + l15;
                ob[(size_t)m * NPOS + n] = acc[ms][ns][r] + xb[(size_t)m * NPOS + n];
            }
        }
}

extern "C" void kernel_launch(void* const* d_in, const int* in_sizes, int n_in,
                              void* d_out, int out_size, void* d_ws, size_t ws_size,
                              hipStream_t stream) {
    const float* x     = (const float*)d_in[0];   // [8][512][32][32] f32
    const float* gamma = (const float*)d_in[1];   // [512] f32
    const float* w_qkv = (const float*)d_in[2];   // [1536][512] f32
    const float* w_out = (const float*)d_in[3];   // [512][512] f32
    float* out = (float*)d_out;                   // [8][512][32][32] f32

    unsigned short* xnT = (unsigned short*)d_ws;             // 8*1024*512 bf16
    unsigned short* wqb = xnT + (size_t)NB * NPOS * NDIM;    // 1536*512
    unsigned short* wob = wqb + (size_t)INNER * NDIM;        // 512*512
    unsigned short* qTw = wob + (size_t)NDIM * NDIM;         // 8*1024*512
    unsigned short* kTw = qTw + (size_t)NB * NPOS * NDIM;
    unsigned short* vvw = kTw + (size_t)NB * NPOS * NDIM;
    unsigned short* aTw = vvw + (size_t)NB * NPOS * NDIM;

    prep_kernel<<<256 + (INNER * NDIM + NDIM * NDIM) / 4 / 256, 256, 0, stream>>>(
        x, gamma, w_qkv, w_out, xnT, wqb, wob);
    qkv_mfma_kernel<<<dim3(NPOS / 128, INNER / 128, NB), 256, 0, stream>>>(
        wqb, xnT, qTw, kTw, vvw);
    attn_mfma8_kernel<<<512, 256, 0, stream>>>(qTw, kTw, vvw, aTw);
    out_mfma_kernel<<<dim3(NPOS / 128, NDIM / 64, NB), 256, 0, stream>>>(wob, aTw, x, out);
}